// Round 1
// baseline (179.801 us; speedup 1.0000x reference)
//
#include <hip/hip_runtime.h>
#include <hip/hip_bf16.h>
#include <math.h>

// Problem constants
#define BB   256   // batch
#define TT   256   // sequence
#define CIN  384   // n_embed
#define HS   64    // head size
#define BT   (BB*TT)

// softmax scale folded into q at projection time: 384^-0.5 * log2(e)
#define QSCL ((float)(0.051031036307982884 * 1.4426950408889634))

typedef __attribute__((ext_vector_type(8))) short short8;   // 8 bf16 = 4 VGPR
typedef __attribute__((ext_vector_type(4))) float floatx4;  // MFMA C/D

__device__ inline short bf16bits(float f) {
    union { __hip_bfloat16 h; short s; } u;
    u.h = __float2bfloat16(f);
    return u.s;
}

__device__ inline short8 cvt8(const float4& f0, const float4& f1) {
    union { __hip_bfloat162 h[4]; short8 s8; } u;
    u.h[0] = __float22bfloat162_rn(make_float2(f0.x, f0.y));
    u.h[1] = __float22bfloat162_rn(make_float2(f0.z, f0.w));
    u.h[2] = __float22bfloat162_rn(make_float2(f1.x, f1.y));
    u.h[3] = __float22bfloat162_rn(make_float2(f1.z, f1.w));
    return u.s8;
}

// ---------------------------------------------------------------------------
// Kernel 0: pack Wq|Wk|Wv into WtP, a per-wave-instruction-contiguous bf16
// layout: for (wn,s,ks,nt) let X = ((wn*6+s)*2+ks)*6+nt; element (l15,quad,j)
// lives at X*512 + l15*32 + quad*8 + j. A B-frag wave load of
// WtP[X*512 + l15*32 + quad*8] is then ONE aligned 1 KB segment.
// ---------------------------------------------------------------------------
__global__ __launch_bounds__(256) void prep_wtp(
    const float* __restrict__ Wq, const float* __restrict__ Wk,
    const float* __restrict__ Wv, short* __restrict__ WtP)
{
    const int idx  = blockIdx.x * 256 + threadIdx.x;   // 0 .. 73727
    const int j    = idx & 7;
    const int quad = (idx >> 3) & 3;
    const int l15  = (idx >> 5) & 15;
    int X          = idx >> 9;          // 0..143
    const int nt   = X % 6;  X /= 6;
    const int ks   = X & 1;  X >>= 1;
    const int s    = X % 6;  X /= 6;
    const int wn   = X;                 // 0..1

    const int n  = wn * 96 + nt * 16 + l15;        // output column 0..191
    const int kk = s * 64 + ks * 32 + quad * 8 + j; // k index 0..383
    const float* W = (n < 64) ? Wq : (n < 128) ? Wk : Wv;
    WtP[idx] = bf16bits(W[kk * 64 + (n & 63)]);
}

// ---------------------------------------------------------------------------
// FUSED kernel: one block per batch element. 512 threads = 8 waves.
//
// Phase 1 (NEW): barrier-free direct-load GEMM. Wave w owns rows
//   [w*32, w*32+32) x full N=192 (acc[2][12]). A-frags are loaded straight
//   from global x (per-lane 8 consecutive fp32 -> cvt8 -> bf16 frag); the
//   wave pattern is 16 rows x 128 B contiguous segments (coalesced). x is
//   read exactly once; B-frags come from the L2-hot WtP layout. There is
//   ZERO LDS traffic and ZERO __syncthreads in phase 1, so the compiler can
//   keep a full slab of loads in flight (no vmcnt(0) barrier drains).
// Epilogue: q (QSCL-prescaled), k, V^T into LDS; single __syncthreads.
// Phase 2: causal attention from LDS; BALANCED wave->row mapping: wave w
//   handles query groups {w, 15-w} (9 causal chunks each vs old 2..16).
//
// LDS (shorts): [0) q [256][72]; [18432) k [256][72];
//   [36864) vt [64][264]; [53760) Ps [8][16][40]; total 117760 B.
// ---------------------------------------------------------------------------
__global__ __launch_bounds__(512) void fused_head(
    const float* __restrict__ x, const short* __restrict__ WtP,
    float* __restrict__ out)
{
    __shared__ short smem[58880];   // 117760 B

    const int tid  = threadIdx.x;
    const int b    = blockIdx.x;
    const int lane = tid & 63;
    const int w    = tid >> 6;        // 0..7
    const int l15  = lane & 15;
    const int quad = lane >> 4;
    const int kq   = quad * 8;
    const int crow = quad * 4;

    const float* xb = x + (size_t)b * 256 * 384;
    const int laneoff = l15 * 32 + quad * 8;       // WtP per-lane offset

    // ---- phase 1: barrier-free, LDS-free GEMM --------------------------
    floatx4 acc[2][12] = {};

    const float* xr0 = xb + (size_t)(w * 32 +      l15) * 384 + kq;  // mt=0
    const float* xr1 = xb + (size_t)(w * 32 + 16 + l15) * 384 + kq;  // mt=1

    float4 cur[2][2][2];   // [mt][ks][half] : current slab's raw fp32
#pragma unroll
    for (int ks = 0; ks < 2; ++ks) {
        cur[0][ks][0] = *(const float4*)(xr0 + ks * 32);
        cur[0][ks][1] = *(const float4*)(xr0 + ks * 32 + 4);
        cur[1][ks][0] = *(const float4*)(xr1 + ks * 32);
        cur[1][ks][1] = *(const float4*)(xr1 + ks * 32 + 4);
    }

#pragma unroll
    for (int s = 0; s < 6; ++s) {
        // issue next slab's loads (1-deep prefetch; no barrier ever drains it)
        float4 nxt[2][2][2];
        if (s < 5) {
#pragma unroll
            for (int ks = 0; ks < 2; ++ks) {
                nxt[0][ks][0] = *(const float4*)(xr0 + (s + 1) * 64 + ks * 32);
                nxt[0][ks][1] = *(const float4*)(xr0 + (s + 1) * 64 + ks * 32 + 4);
                nxt[1][ks][0] = *(const float4*)(xr1 + (s + 1) * 64 + ks * 32);
                nxt[1][ks][1] = *(const float4*)(xr1 + (s + 1) * 64 + ks * 32 + 4);
            }
        }

#pragma unroll
        for (int ks = 0; ks < 2; ++ks) {
            short8 af0 = cvt8(cur[0][ks][0], cur[0][ks][1]);
            short8 af1 = cvt8(cur[1][ks][0], cur[1][ks][1]);
#pragma unroll
            for (int h = 0; h < 2; ++h)
#pragma unroll
                for (int nt = 0; nt < 6; ++nt) {
                    const short8 bf = *(const short8*)
                        &WtP[((((h * 6 + s) * 2 + ks) * 6 + nt) << 9) + laneoff];
                    const int j = h * 6 + nt;
                    acc[0][j] = __builtin_amdgcn_mfma_f32_16x16x32_bf16(
                        af0, bf, acc[0][j], 0, 0, 0);
                    acc[1][j] = __builtin_amdgcn_mfma_f32_16x16x32_bf16(
                        af1, bf, acc[1][j], 0, 0, 0);
                }
        }

        if (s < 5) {
#pragma unroll
            for (int mt = 0; mt < 2; ++mt)
#pragma unroll
                for (int ks = 0; ks < 2; ++ks) {
                    cur[mt][ks][0] = nxt[mt][ks][0];
                    cur[mt][ks][1] = nxt[mt][ks][1];
                }
        }
    }

    // ---- epilogue: q/k/vT into LDS (branch on j is compile-time) -------
    short* q_lds = smem;             // [256][72]
    short* k_lds = smem + 18432;     // [256][72]
    short* vt    = smem + 36864;     // [64][264]
    short* Ps    = smem + 53760;     // [8][16][40]

#pragma unroll
    for (int mt = 0; mt < 2; ++mt)
#pragma unroll
        for (int j = 0; j < 12; ++j) {
            const int n = j * 16 + l15;
#pragma unroll
            for (int r = 0; r < 4; ++r) {
                const int m = w * 32 + mt * 16 + crow + r;   // token row
                const float av = acc[mt][j][r];
                if (j < 4)      q_lds[m * 72 + n]          = bf16bits(av * QSCL);
                else if (j < 8) k_lds[m * 72 + (n - 64)]   = bf16bits(av);
                else            vt[(n - 128) * 264 + m]    = bf16bits(av);
            }
        }
    __syncthreads();

    // ---- phase 2: attention. wave w owns groups {w, 15-w}: 9 chunks each
#pragma unroll
    for (int g = 0; g < 2; ++g) {
        const int grp = g ? (15 - w) : w;
        const int r0  = grp * 16;

        short8 aq0, aq1;
        aq0 = *(const short8*)&q_lds[(r0 + l15) * 72 + kq];
        aq1 = *(const short8*)&q_lds[(r0 + l15) * 72 + 32 + kq];

        float lsum[4] = {0.f, 0.f, 0.f, 0.f};
        floatx4 O[4] = {};

        const int nch = (r0 + 47) >> 5;   // chunks of 32 keys, causal bound
        for (int c = 0; c < nch; ++c) {
            const int cb = c * 32;

            floatx4 st[2];
#pragma unroll
            for (int t = 0; t < 2; ++t) {
                const short8 b0 = *(const short8*)&k_lds[(cb + t * 16 + l15) * 72 + kq];
                const short8 b1 = *(const short8*)&k_lds[(cb + t * 16 + l15) * 72 + 32 + kq];
                floatx4 z = {};
                z = __builtin_amdgcn_mfma_f32_16x16x32_bf16(aq0, b0, z, 0, 0, 0);
                z = __builtin_amdgcn_mfma_f32_16x16x32_bf16(aq1, b1, z, 0, 0, 0);
                st[t] = z;
            }

#pragma unroll
            for (int t = 0; t < 2; ++t)
#pragma unroll
                for (int r = 0; r < 4; ++r) {
                    const int key  = cb + t * 16 + l15;
                    const int qrow = r0 + crow + r;
                    float p = __builtin_amdgcn_exp2f(st[t][r]);
                    p = (key <= qrow) ? p : 0.f;
                    lsum[r] += p;
                    Ps[w * 640 + (crow + r) * 40 + t * 16 + l15] = bf16bits(p);
                }

            // wave-private LDS write->read ordering
            asm volatile("s_waitcnt lgkmcnt(0)" ::: "memory");

            const short8 pa = *(const short8*)&Ps[w * 640 + l15 * 40 + kq];
#pragma unroll
            for (int n = 0; n < 4; ++n) {
                const short8 bv = *(const short8*)&vt[(n * 16 + l15) * 264 + cb + kq];
                O[n] = __builtin_amdgcn_mfma_f32_16x16x32_bf16(pa, bv, O[n], 0, 0, 0);
            }
        }

#pragma unroll
        for (int off = 1; off < 16; off <<= 1)
#pragma unroll
            for (int r = 0; r < 4; ++r)
                lsum[r] += __shfl_xor(lsum[r], off, 16);

        float inv[4];
#pragma unroll
        for (int r = 0; r < 4; ++r) inv[r] = 1.f / lsum[r];
#pragma unroll
        for (int n = 0; n < 4; ++n)
#pragma unroll
            for (int r = 0; r < 4; ++r)
                out[(size_t)(b * 256 + r0 + crow + r) * 64 + n * 16 + l15] = O[n][r] * inv[r];
    }
}

// ---------------------------------------------------------------------------
// Launch
// ---------------------------------------------------------------------------
extern "C" void kernel_launch(void* const* d_in, const int* in_sizes, int n_in,
                              void* d_out, int out_size, void* d_ws, size_t ws_size,
                              hipStream_t stream)
{
    const float* x  = (const float*)d_in[0];
    const float* Wq = (const float*)d_in[1];
    const float* Wk = (const float*)d_in[2];
    const float* Wv = (const float*)d_in[3];
    float* out = (float*)d_out;

    short* WtP = (short*)d_ws;   // 73728 bf16 = 147456 B

    prep_wtp<<<(192 * 384) / 256, 256, 0, stream>>>(Wq, Wk, Wv, WtP);
    fused_head<<<BB, 512, 0, stream>>>(x, WtP, out);
}